// Round 5
// baseline (191.600 us; speedup 1.0000x reference)
//
#include <hip/hip_runtime.h>
#include <hip/hip_bf16.h>

// MHA block: x[4096,1024] fp32; Wq/Wk/Wv/Wo [1024,1024] fp32.
// R15: two edits, separately attributable per-dispatch:
//  (1) attn: counted-vmcnt 3-buffer pipeline. __syncthreads drains vmcnt(0);
//      replaced with asm s_waitcnt vmcnt(2) + raw s_barrier, 3 LDS buffers,
//      prefetch distance 2 (stage s+2 issued in step s). RAW: vmcnt(2) with
//      in-order retirement => stage(s) landed before barrier. WAR: buf
//      (s+2)%3 == (s-1)%3, reads finished before this barrier in program
//      order; asm "memory" clobber pins ds_reads below the wait. Tail uses
//      wrapped dummy stages (uniform vmcnt algebra; dummies write buffers
//      never read again). s_setprio(1) around MFMA cluster (T5; counted
//      vmcnt creates the wave role-split it needs).
//  (2) GEMMs: 128x128 tile (m97 structure): 4 waves x 64x64 quadrant,
//      acc[4][4], Bs widened to 128x64. Epilogue routes unchanged (wave
//      columns 64-aligned => region-uniform).
// Keeps: 8 waves x 32 q-rows attn geometry (R14), magic-mantissa exp2,
//  S^T trick, MFMA l-sums, key-interleaved V^T, casts.

typedef __bf16 bf16_t;
typedef __bf16 bf16x8 __attribute__((ext_vector_type(8)));
typedef __bf16 bf16x4 __attribute__((ext_vector_type(4)));
typedef float f32x4 __attribute__((ext_vector_type(4)));

#define D_MODEL 1024
#define SEQ 4096
#define HEADS 16
#define DK 64
#define QSCALE 0.1803368801111204f  // log2(e)/8
#define EXP2_MAGIC 8404859.0f       // 2^23 + 16251 (integer-exact float)

// ---------------- casts fp32 -> bf16 ----------------
__global__ void cast_kernel(const float* __restrict__ in, bf16_t* __restrict__ out, int n) {
    int i = (blockIdx.x * blockDim.x + threadIdx.x) * 4;
    if (i < n) {
        float4 v = *(const float4*)(in + i);
        bf16x4 o;
        o[0] = (bf16_t)v.x; o[1] = (bf16_t)v.y; o[2] = (bf16_t)v.z; o[3] = (bf16_t)v.w;
        *(bf16x4*)(out + i) = o;
    }
}

__global__ void cast4_kernel(const float* __restrict__ a, const float* __restrict__ b,
                             const float* __restrict__ c, const float* __restrict__ d,
                             bf16_t* __restrict__ out) {
    int gi = blockIdx.x * blockDim.x + threadIdx.x;
    int which = gi >> 18;
    int i = (gi & 0x3FFFF) * 4;
    const float* src = which == 0 ? a : which == 1 ? b : which == 2 ? c : d;
    float4 v = *(const float4*)(src + i);
    bf16x4 o;
    o[0] = (bf16_t)v.x; o[1] = (bf16_t)v.y; o[2] = (bf16_t)v.z; o[3] = (bf16_t)v.w;
    *(bf16x4*)(out + (size_t)which * D_MODEL * D_MODEL + i) = o;
}

__device__ __forceinline__ void g2l16(const bf16_t* g, bf16_t* l) {
    __builtin_amdgcn_global_load_lds(
        (const __attribute__((address_space(1))) void*)g,
        (__attribute__((address_space(3))) void*)l, 16, 0, 0);
}

// Schraudolph exp2 -> packed bf16x8: slots 0-3 = 2^a[r], 4-7 = 2^b[r].
// fma into [2^23,2^24): low 16 float bits ARE the bf16 bits; v_perm packs.
__device__ __forceinline__ bf16x8 exp2_pk(const f32x4 a, const f32x4 b) {
    union { float f; unsigned u; } v[8];
#pragma unroll
    for (int r = 0; r < 4; r++) {
        v[r].f     = fmaf(a[r], 128.0f, EXP2_MAGIC);
        v[r + 4].f = fmaf(b[r], 128.0f, EXP2_MAGIC);
    }
    union { unsigned u[4]; bf16x8 h; } o;
#pragma unroll
    for (int p = 0; p < 4; p++)
        o.u[p] = __builtin_amdgcn_perm(v[2 * p + 1].u, v[2 * p].u, 0x05040100u);
    return o.h;
}

// ---------------- LDS-staged NT GEMM, 128x128 tile ----------------
// ROUTE 1: QKV split; V^T written key-interleaved (see header comment).
template <int ROUTE>
__global__ __launch_bounds__(256, 2) void gemm_lds(const bf16_t* __restrict__ A,
                                                   const bf16_t* __restrict__ B,
                                                   void* __restrict__ out0,
                                                   void* __restrict__ out1,
                                                   void* __restrict__ out2,
                                                   int M, int N, int K) {
    __shared__ __align__(16) bf16_t As[128 * 64];
    __shared__ __align__(16) bf16_t Bs[128 * 64];

    const int tid = threadIdx.x;
    const int lane = tid & 63;
    const int wave = tid >> 6;
    const int l15 = lane & 15;
    const int lg  = lane >> 4;
    const int m0 = blockIdx.y * 128;
    const int n0 = blockIdx.x * 128;
    const int wm = (wave >> 1) * 64;
    const int wn = (wave & 1) * 64;

    const bf16_t* aSrc[4]; bf16_t* aDst[4];
    const bf16_t* bSrc[4]; bf16_t* bDst[4];
#pragma unroll
    for (int it = 0; it < 4; it++) {
        int c = it * 256 + tid;
        int row = c >> 3, cc = (c & 7) ^ (row & 7);
        aSrc[it] = A + (size_t)(m0 + row) * K + cc * 8;
        aDst[it] = As + c * 8;
        bSrc[it] = B + (size_t)(n0 + row) * K + cc * 8;
        bDst[it] = Bs + c * 8;
    }

    int aoff[2][4], boff[2][4];
#pragma unroll
    for (int kk = 0; kk < 2; kk++) {
#pragma unroll
        for (int i = 0; i < 4; i++) {
            int row = wm + i * 16 + l15;
            aoff[kk][i] = row * 64 + (((kk << 2) | lg) ^ (row & 7)) * 8;
        }
#pragma unroll
        for (int j = 0; j < 4; j++) {
            int row = wn + j * 16 + l15;
            boff[kk][j] = row * 64 + (((kk << 2) | lg) ^ (row & 7)) * 8;
        }
    }

    f32x4 acc[4][4];
#pragma unroll
    for (int i = 0; i < 4; i++)
#pragma unroll
        for (int j = 0; j < 4; j++) acc[i][j] = f32x4{0.f, 0.f, 0.f, 0.f};

    for (int k0 = 0; k0 < K; k0 += 64) {
#pragma unroll
        for (int it = 0; it < 4; it++) g2l16(aSrc[it] + k0, aDst[it]);
#pragma unroll
        for (int it = 0; it < 4; it++) g2l16(bSrc[it] + k0, bDst[it]);
        __syncthreads();

#pragma unroll
        for (int kk = 0; kk < 2; kk++) {
            bf16x8 af[4], bfm[4];
#pragma unroll
            for (int i = 0; i < 4; i++) af[i] = *(const bf16x8*)(As + aoff[kk][i]);
#pragma unroll
            for (int j = 0; j < 4; j++) bfm[j] = *(const bf16x8*)(Bs + boff[kk][j]);
#pragma unroll
            for (int i = 0; i < 4; i++)
#pragma unroll
                for (int j = 0; j < 4; j++)
                    acc[i][j] = __builtin_amdgcn_mfma_f32_16x16x32_bf16(af[i], bfm[j], acc[i][j], 0, 0, 0);
        }
        __syncthreads();
    }

    const int ng = n0 + wn;  // 64-aligned -> region-uniform per wave
    if (ROUTE == 0) {
        float* C = (float*)out0;
#pragma unroll
        for (int i = 0; i < 4; i++)
#pragma unroll
            for (int r = 0; r < 4; r++) {
                int m = m0 + wm + i * 16 + lg * 4 + r;
                float* crow = C + (size_t)m * N + ng;
#pragma unroll
                for (int j = 0; j < 4; j++) crow[j * 16 + l15] = acc[i][j][r];
            }
    } else {
        if (ng < 2048) {
            const bool isQ = (ng < 1024);
            const float sc = isQ ? QSCALE : 1.0f;
            bf16_t* dst = isQ ? (bf16_t*)out0 : (bf16_t*)out1;
            int nn = ng & 1023;
#pragma unroll
            for (int i = 0; i < 4; i++)
#pragma unroll
                for (int r = 0; r < 4; r++) {
                    int m = m0 + wm + i * 16 + lg * 4 + r;
                    bf16_t* crow = dst + (size_t)m * D_MODEL + nn;
#pragma unroll
                    for (int j = 0; j < 4; j++) crow[j * 16 + l15] = (bf16_t)(acc[i][j][r] * sc);
                }
        } else {
            bf16_t* Vt = (bf16_t*)out2;
#pragma unroll
            for (int i = 0; i < 4; i++)
#pragma unroll
                for (int j = 0; j < 4; j++) {
                    int vcol = ng - 2048 + j * 16 + l15;
                    int m = m0 + wm + i * 16 + lg * 4;  // multiple of 4
                    // key-interleave within 32-key block: pos = g*8 + sub*4 + r
                    int mp = (m & ~31) | (((m >> 2) & 3) << 3) | (((m >> 4) & 1) << 2);
                    bf16x4 v4;
#pragma unroll
                    for (int r = 0; r < 4; r++) v4[r] = (bf16_t)acc[i][j][r];
                    *(bf16x4*)(Vt + (size_t)vcol * SEQ + mp) = v4;
                }
        }
    }
}

// ---- attention: 8 waves x 32 q-rows, 3-buf counted-vmcnt, direct store ----
__global__ __launch_bounds__(512, 2) void attn_kernel(const bf16_t* __restrict__ Q,
                                                      const bf16_t* __restrict__ Km,
                                                      const bf16_t* __restrict__ Vt,
                                                      bf16_t* __restrict__ O) {
    const int tid = threadIdx.x;
    const int lane = tid & 63;
    const int wave = tid >> 6;   // 0..7, each owns 32 q-rows
    const int l15 = lane & 15;
    const int lg  = lane >> 4;
    const int bid = blockIdx.x;
    const int h    = (bid & 7) * 2 + ((bid >> 3) & 1);  // 2 heads/XCD -> K/V L2-resident
    const int qblk = bid >> 4;   // 0..15
    const int q0 = qblk * 256;
    const int hoff = h * DK;

    __shared__ struct {
        __align__(16) bf16_t K[3][64 * 64];
        __align__(16) bf16_t V[3][64 * 64];
    } sm;

    bf16x8 qf[2][2];
#pragma unroll
    for (int t = 0; t < 2; t++)
#pragma unroll
        for (int c = 0; c < 2; c++)
            qf[t][c] = *(const bf16x8*)(Q + (size_t)(q0 + wave * 32 + t * 16 + l15) * D_MODEL
                                        + hoff + c * 32 + lg * 8);

    f32x4 oacc[2][4], lfrag[2];
#pragma unroll
    for (int t = 0; t < 2; t++) {
        lfrag[t] = f32x4{0.f, 0.f, 0.f, 0.f};
#pragma unroll
        for (int dt = 0; dt < 4; dt++) oacc[t][dt] = f32x4{0.f, 0.f, 0.f, 0.f};
    }

    bf16x8 ones8;
#pragma unroll
    for (int j = 0; j < 8; j++) ones8[j] = (bf16_t)1.0f;

    // staging: 512 threads x one 16B chunk per tile (64x64 bf16 = 8KB each)
    const int srow = tid >> 3;
    const int sdc = (tid & 7) ^ (srow & 7);
    const bf16_t* kSrc = Km + (size_t)srow * D_MODEL + hoff + sdc * 8;
    const bf16_t* vSrc = Vt + (size_t)(hoff + srow) * SEQ + sdc * 8;

    int kOff[4][2], vOff[2][4];
#pragma unroll
    for (int kt = 0; kt < 4; kt++)
#pragma unroll
        for (int c = 0; c < 2; c++) {
            int row = kt * 16 + l15;
            kOff[kt][c] = row * 64 + (((c * 4 + lg) ^ (row & 7)) * 8);
        }
#pragma unroll
    for (int kp = 0; kp < 2; kp++)
#pragma unroll
        for (int dt = 0; dt < 4; dt++) {
            int row = dt * 16 + l15;
            // single b128: interleaved keys, column kp*32 + lg*8
            vOff[kp][dt] = row * 64 + (((kp * 4 + lg) ^ (row & 7)) * 8);
        }

    // prologue: stage tiles 0 and 1 (issue order = vmcnt age order)
    g2l16(kSrc,                           &sm.K[0][tid * 8]);
    g2l16(vSrc,                           &sm.V[0][tid * 8]);
    g2l16(kSrc + (size_t)64 * D_MODEL,    &sm.K[1][tid * 8]);
    g2l16(vSrc + 64,                      &sm.V[1][tid * 8]);

    int cur = 0, nb = 2;
    for (int s = 0; s < SEQ / 64; s++) {
        // wait: everything except the newest 2 loads (= stage(s+1)) done
        // -> stage(s) complete. In-order vmcnt retirement (m135).
        asm volatile("s_waitcnt vmcnt(2)" ::: "memory");
        __builtin_amdgcn_s_barrier();

        // stage s+2 into buf (s+2)%3 == (s-1)%3 (its reads finished before
        // the barrier above). Tail wraps to dummy reloads of tiles 0/1 into
        // never-again-read buffers: keeps vmcnt counts uniform.
        const int s2 = (s + 2) & (SEQ / 64 - 1);
        g2l16(kSrc + (size_t)s2 * 64 * D_MODEL, &sm.K[nb][tid * 8]);
        g2l16(vSrc + s2 * 64,                   &sm.V[nb][tid * 8]);

        const bf16_t* Kb = sm.K[cur];
        const bf16_t* Vb = sm.V[cur];

        __builtin_amdgcn_s_setprio(1);
#pragma unroll
        for (int kp = 0; kp < 2; kp++) {
            bf16x8 vf[4];
#pragma unroll
            for (int dt = 0; dt < 4; dt++) vf[dt] = *(const bf16x8*)(Vb + vOff[kp][dt]);

            f32x4 st[2][2];
#pragma unroll
            for (int sub = 0; sub < 2; sub++) {
                const int kt = kp * 2 + sub;
                const bf16x8 kf0 = *(const bf16x8*)(Kb + kOff[kt][0]);
                const bf16x8 kf1 = *(const bf16x8*)(Kb + kOff[kt][1]);
#pragma unroll
                for (int t = 0; t < 2; t++) {
                    f32x4 a = f32x4{0.f, 0.f, 0.f, 0.f};
                    a = __builtin_amdgcn_mfma_f32_16x16x32_bf16(kf0, qf[t][0], a, 0, 0, 0);
                    a = __builtin_amdgcn_mfma_f32_16x16x32_bf16(kf1, qf[t][1], a, 0, 0, 0);
                    st[t][sub] = a;
                }
            }

#pragma unroll
            for (int t = 0; t < 2; t++) {
                const bf16x8 pbig = exp2_pk(st[t][0], st[t][1]);
                lfrag[t] = __builtin_amdgcn_mfma_f32_16x16x32_bf16(ones8, pbig, lfrag[t], 0, 0, 0);
#pragma unroll
                for (int dt = 0; dt < 4; dt++)
                    oacc[t][dt] = __builtin_amdgcn_mfma_f32_16x16x32_bf16(vf[dt], pbig, oacc[t][dt], 0, 0, 0);
            }
        }
        __builtin_amdgcn_s_setprio(0);

        cur = (cur == 2) ? 0 : cur + 1;
        nb  = (nb  == 2) ? 0 : nb + 1;
    }

    // direct store: col = query (lane-local l), row band = d
#pragma unroll
    for (int t = 0; t < 2; t++) {
        const float inv = 1.f / lfrag[t][0];
        const size_t qrow = (size_t)(q0 + wave * 32 + t * 16 + l15);
#pragma unroll
        for (int dt = 0; dt < 4; dt++) {
            bf16x4 o4;
#pragma unroll
            for (int r = 0; r < 4; r++) o4[r] = (bf16_t)(oacc[t][dt][r] * inv);
            *(bf16x4*)(O + qrow * D_MODEL + hoff + dt * 16 + lg * 4) = o4;
        }
    }
}

// ---------------- launcher ----------------
extern "C" void kernel_launch(void* const* d_in, const int* in_sizes, int n_in,
                              void* d_out, int out_size, void* d_ws, size_t ws_size,
                              hipStream_t stream) {
    const float* x  = (const float*)d_in[0];
    const float* Wq = (const float*)d_in[1];
    const float* Wk = (const float*)d_in[2];
    const float* Wv = (const float*)d_in[3];
    const float* Wo = (const float*)d_in[4];
    float* out = (float*)d_out;

    char* ws = (char*)d_ws;
    bf16_t* xb  = (bf16_t*)(ws);
    bf16_t* wqb = (bf16_t*)(ws + (8u  << 20));
    bf16_t* wob = (bf16_t*)(ws + (14u << 20));
    bf16_t* Qb  = (bf16_t*)(ws + (16u << 20));
    bf16_t* Kb  = (bf16_t*)(ws + (24u << 20));
    bf16_t* Vtb = (bf16_t*)(ws + (32u << 20));
    bf16_t* Ab  = (bf16_t*)(ws + (40u << 20));

    const int nX = SEQ * D_MODEL;
    cast_kernel<<<nX / 4 / 256, 256, 0, stream>>>(x, xb, nX);
    cast4_kernel<<<4 * 1024, 256, 0, stream>>>(Wq, Wk, Wv, Wo, wqb);

    gemm_lds<1><<<dim3(3 * D_MODEL / 128, SEQ / 128), 256, 0, stream>>>(
        xb, wqb, Qb, Kb, Vtb, SEQ, 3 * D_MODEL, D_MODEL);

    attn_kernel<<<256, 512, 0, stream>>>(Qb, Kb, Vtb, Ab);

    gemm_lds<0><<<dim3(D_MODEL / 128, SEQ / 128), 256, 0, stream>>>(
        Ab, wob, out, nullptr, nullptr, SEQ, D_MODEL, D_MODEL);
}

// Round 6
// 185.426 us; speedup vs baseline: 1.0333x; 1.0333x over previous
//
#include <hip/hip_runtime.h>
#include <hip/hip_bf16.h>

// MHA block: x[4096,1024] fp32; Wq/Wk/Wv/Wo [1024,1024] fp32.
// R16: consolidation + GEMM locality.
//  (1) attn reverted to R14 exact (69.5us proven): 8 waves x 32 q-rows,
//      2-buffer g2l16 + __syncthreads. R15's counted-vmcnt/setprio was -3.5us:
//      with prefetch distance 1 the loads have ~2600cyc to land vs ~200-900
//      latency -> the vmcnt(0) drain was already free (T4 needs fine phases).
//  (2) GEMMs: bijective XCD swizzle (T1). Each XCD owns gridDim.y/8
//      consecutive m-panels (m-fastest in chunk, n streamed): per-XCD A
//      working set 1MB (L2-resident), B read once per 4-m group. Cuts
//      ~400MB L2-miss traffic to ~60MB. Explains why 128^2 tile alone
//      under-delivered (locality-bound, not compute-bound).
//  (3) casts merged into one kernel (one fewer launch/gap).
// Keeps: 128x128 GEMM tile (R15), magic-mantissa exp2, S^T trick,
//  MFMA l-sums, key-interleaved V^T.

typedef __bf16 bf16_t;
typedef __bf16 bf16x8 __attribute__((ext_vector_type(8)));
typedef __bf16 bf16x4 __attribute__((ext_vector_type(4)));
typedef float f32x4 __attribute__((ext_vector_type(4)));

#define D_MODEL 1024
#define SEQ 4096
#define HEADS 16
#define DK 64
#define QSCALE 0.1803368801111204f  // log2(e)/8
#define EXP2_MAGIC 8404859.0f       // 2^23 + 16251 (integer-exact float)

// ---------------- fused casts fp32 -> bf16 ----------------
__global__ void cast_all(const float* __restrict__ x, const float* __restrict__ a,
                         const float* __restrict__ b, const float* __restrict__ c,
                         const float* __restrict__ d, bf16_t* __restrict__ xb,
                         bf16_t* __restrict__ wb) {
    const int gi = blockIdx.x * blockDim.x + threadIdx.x;
    const float* src; bf16_t* dst; int i;
    if (gi < SEQ * D_MODEL / 4) {
        src = x; dst = xb; i = gi * 4;
    } else {
        int g = gi - SEQ * D_MODEL / 4;
        int which = g >> 18;
        src = which == 0 ? a : which == 1 ? b : which == 2 ? c : d;
        dst = wb + (size_t)which * D_MODEL * D_MODEL;
        i = (g & 0x3FFFF) * 4;
    }
    float4 v = *(const float4*)(src + i);
    bf16x4 o;
    o[0] = (bf16_t)v.x; o[1] = (bf16_t)v.y; o[2] = (bf16_t)v.z; o[3] = (bf16_t)v.w;
    *(bf16x4*)(dst + i) = o;
}

__device__ __forceinline__ void g2l16(const bf16_t* g, bf16_t* l) {
    __builtin_amdgcn_global_load_lds(
        (const __attribute__((address_space(1))) void*)g,
        (__attribute__((address_space(3))) void*)l, 16, 0, 0);
}

// Schraudolph exp2 -> packed bf16x8: slots 0-3 = 2^a[r], 4-7 = 2^b[r].
// fma into [2^23,2^24): low 16 float bits ARE the bf16 bits; v_perm packs.
__device__ __forceinline__ bf16x8 exp2_pk(const f32x4 a, const f32x4 b) {
    union { float f; unsigned u; } v[8];
#pragma unroll
    for (int r = 0; r < 4; r++) {
        v[r].f     = fmaf(a[r], 128.0f, EXP2_MAGIC);
        v[r + 4].f = fmaf(b[r], 128.0f, EXP2_MAGIC);
    }
    union { unsigned u[4]; bf16x8 h; } o;
#pragma unroll
    for (int p = 0; p < 4; p++)
        o.u[p] = __builtin_amdgcn_perm(v[2 * p + 1].u, v[2 * p].u, 0x05040100u);
    return o.h;
}

// ---------------- LDS-staged NT GEMM, 128x128 tile, XCD swizzle ----------
// ROUTE 1: QKV split; V^T written key-interleaved (see header comment).
template <int ROUTE>
__global__ __launch_bounds__(256, 2) void gemm_lds(const bf16_t* __restrict__ A,
                                                   const bf16_t* __restrict__ B,
                                                   void* __restrict__ out0,
                                                   void* __restrict__ out1,
                                                   void* __restrict__ out2,
                                                   int M, int N, int K) {
    __shared__ __align__(16) bf16_t As[128 * 64];
    __shared__ __align__(16) bf16_t Bs[128 * 64];

    const int tid = threadIdx.x;
    const int lane = tid & 63;
    const int wave = tid >> 6;
    const int l15 = lane & 15;
    const int lg  = lane >> 4;

    // XCD-aware bijective remap (requires nwg%8==0; gridDim.y%8==0):
    // xcd = flat%8 owns m-panels [xcd*mpx, (xcd+1)*mpx), m-fastest in chunk
    // -> A resident in per-XCD L2, B panel reused across mpx consecutive
    // blocks before n advances.
    const int flat = blockIdx.y * gridDim.x + blockIdx.x;
    const int mpx  = gridDim.y >> 3;          // m-panels per XCD
    const int xcd  = flat & 7;
    const int pos  = flat >> 3;
    const int m0 = (xcd * mpx + (pos % mpx)) * 128;
    const int n0 = (pos / mpx) * 128;
    const int wm = (wave >> 1) * 64;
    const int wn = (wave & 1) * 64;

    const bf16_t* aSrc[4]; bf16_t* aDst[4];
    const bf16_t* bSrc[4]; bf16_t* bDst[4];
#pragma unroll
    for (int it = 0; it < 4; it++) {
        int c = it * 256 + tid;
        int row = c >> 3, cc = (c & 7) ^ (row & 7);
        aSrc[it] = A + (size_t)(m0 + row) * K + cc * 8;
        aDst[it] = As + c * 8;
        bSrc[it] = B + (size_t)(n0 + row) * K + cc * 8;
        bDst[it] = Bs + c * 8;
    }

    int aoff[2][4], boff[2][4];
#pragma unroll
    for (int kk = 0; kk < 2; kk++) {
#pragma unroll
        for (int i = 0; i < 4; i++) {
            int row = wm + i * 16 + l15;
            aoff[kk][i] = row * 64 + (((kk << 2) | lg) ^ (row & 7)) * 8;
        }
#pragma unroll
        for (int j = 0; j < 4; j++) {
            int row = wn + j * 16 + l15;
            boff[kk][j] = row * 64 + (((kk << 2) | lg) ^ (row & 7)) * 8;
        }
    }

    f32x4 acc[4][4];
#pragma unroll
    for (int i = 0; i < 4; i++)
#pragma unroll
        for (int j = 0; j < 4; j++) acc[i][j] = f32x4{0.f, 0.f, 0.f, 0.f};

    for (int k0 = 0; k0 < K; k0 += 64) {
#pragma unroll
        for (int it = 0; it < 4; it++) g2l16(aSrc[it] + k0, aDst[it]);
#pragma unroll
        for (int it = 0; it < 4; it++) g2l16(bSrc[it] + k0, bDst[it]);
        __syncthreads();

#pragma unroll
        for (int kk = 0; kk < 2; kk++) {
            bf16x8 af[4], bfm[4];
#pragma unroll
            for (int i = 0; i < 4; i++) af[i] = *(const bf16x8*)(As + aoff[kk][i]);
#pragma unroll
            for (int j = 0; j < 4; j++) bfm[j] = *(const bf16x8*)(Bs + boff[kk][j]);
#pragma unroll
            for (int i = 0; i < 4; i++)
#pragma unroll
                for (int j = 0; j < 4; j++)
                    acc[i][j] = __builtin_amdgcn_mfma_f32_16x16x32_bf16(af[i], bfm[j], acc[i][j], 0, 0, 0);
        }
        __syncthreads();
    }

    const int ng = n0 + wn;  // 64-aligned -> region-uniform per wave
    if (ROUTE == 0) {
        float* C = (float*)out0;
#pragma unroll
        for (int i = 0; i < 4; i++)
#pragma unroll
            for (int r = 0; r < 4; r++) {
                int m = m0 + wm + i * 16 + lg * 4 + r;
                float* crow = C + (size_t)m * N + ng;
#pragma unroll
                for (int j = 0; j < 4; j++) crow[j * 16 + l15] = acc[i][j][r];
            }
    } else {
        if (ng < 2048) {
            const bool isQ = (ng < 1024);
            const float sc = isQ ? QSCALE : 1.0f;
            bf16_t* dst = isQ ? (bf16_t*)out0 : (bf16_t*)out1;
            int nn = ng & 1023;
#pragma unroll
            for (int i = 0; i < 4; i++)
#pragma unroll
                for (int r = 0; r < 4; r++) {
                    int m = m0 + wm + i * 16 + lg * 4 + r;
                    bf16_t* crow = dst + (size_t)m * D_MODEL + nn;
#pragma unroll
                    for (int j = 0; j < 4; j++) crow[j * 16 + l15] = (bf16_t)(acc[i][j][r] * sc);
                }
        } else {
            bf16_t* Vt = (bf16_t*)out2;
#pragma unroll
            for (int i = 0; i < 4; i++)
#pragma unroll
                for (int j = 0; j < 4; j++) {
                    int vcol = ng - 2048 + j * 16 + l15;
                    int m = m0 + wm + i * 16 + lg * 4;  // multiple of 4
                    // key-interleave within 32-key block: pos = g*8 + sub*4 + r
                    int mp = (m & ~31) | (((m >> 2) & 3) << 3) | (((m >> 4) & 1) << 2);
                    bf16x4 v4;
#pragma unroll
                    for (int r = 0; r < 4; r++) v4[r] = (bf16_t)acc[i][j][r];
                    *(bf16x4*)(Vt + (size_t)vcol * SEQ + mp) = v4;
                }
        }
    }
}

// ---- attention: 8 waves x 32 q-rows, LDS dbuf, direct store, grid 256 ----
// (R14 verbatim — proven 69.5us / tripwire-clean)
__global__ __launch_bounds__(512, 2) void attn_kernel(const bf16_t* __restrict__ Q,
                                                      const bf16_t* __restrict__ Km,
                                                      const bf16_t* __restrict__ Vt,
                                                      bf16_t* __restrict__ O) {
    const int tid = threadIdx.x;
    const int lane = tid & 63;
    const int wave = tid >> 6;   // 0..7, each owns 32 q-rows
    const int l15 = lane & 15;
    const int lg  = lane >> 4;
    const int bid = blockIdx.x;
    const int h    = (bid & 7) * 2 + ((bid >> 3) & 1);  // 2 heads/XCD -> K/V L2-resident
    const int qblk = bid >> 4;   // 0..15
    const int q0 = qblk * 256;
    const int hoff = h * DK;

    __shared__ struct {
        __align__(16) bf16_t K[2][64 * 64];
        __align__(16) bf16_t V[2][64 * 64];
    } sm;

    bf16x8 qf[2][2];
#pragma unroll
    for (int t = 0; t < 2; t++)
#pragma unroll
        for (int c = 0; c < 2; c++)
            qf[t][c] = *(const bf16x8*)(Q + (size_t)(q0 + wave * 32 + t * 16 + l15) * D_MODEL
                                        + hoff + c * 32 + lg * 8);

    f32x4 oacc[2][4], lfrag[2];
#pragma unroll
    for (int t = 0; t < 2; t++) {
        lfrag[t] = f32x4{0.f, 0.f, 0.f, 0.f};
#pragma unroll
        for (int dt = 0; dt < 4; dt++) oacc[t][dt] = f32x4{0.f, 0.f, 0.f, 0.f};
    }

    bf16x8 ones8;
#pragma unroll
    for (int j = 0; j < 8; j++) ones8[j] = (bf16_t)1.0f;

    // staging: 512 threads x one 16B chunk per tile (64x64 bf16 = 8KB each)
    const int srow = tid >> 3;
    const int sdc = (tid & 7) ^ (srow & 7);
    const bf16_t* kSrc = Km + (size_t)srow * D_MODEL + hoff + sdc * 8;
    const bf16_t* vSrc = Vt + (size_t)(hoff + srow) * SEQ + sdc * 8;

    int kOff[4][2], vOff[2][4];
#pragma unroll
    for (int kt = 0; kt < 4; kt++)
#pragma unroll
        for (int c = 0; c < 2; c++) {
            int row = kt * 16 + l15;
            kOff[kt][c] = row * 64 + (((c * 4 + lg) ^ (row & 7)) * 8);
        }
#pragma unroll
    for (int kp = 0; kp < 2; kp++)
#pragma unroll
        for (int dt = 0; dt < 4; dt++) {
            int row = dt * 16 + l15;
            // single b128: interleaved keys, column kp*32 + lg*8
            vOff[kp][dt] = row * 64 + (((kp * 4 + lg) ^ (row & 7)) * 8);
        }

    // prologue: stage step 0 into buffer 0
    g2l16(kSrc, &sm.K[0][tid * 8]);
    g2l16(vSrc, &sm.V[0][tid * 8]);

    for (int s = 0; s < SEQ / 64; s++) {
        const int cur = s & 1;
        __syncthreads();

        if (s + 1 < SEQ / 64) {
            const int nxt = cur ^ 1;
            g2l16(kSrc + (size_t)(s + 1) * 64 * D_MODEL, &sm.K[nxt][tid * 8]);
            g2l16(vSrc + (s + 1) * 64,                   &sm.V[nxt][tid * 8]);
        }

        const bf16_t* Kb = sm.K[cur];
        const bf16_t* Vb = sm.V[cur];

#pragma unroll
        for (int kp = 0; kp < 2; kp++) {
            bf16x8 vf[4];
#pragma unroll
            for (int dt = 0; dt < 4; dt++) vf[dt] = *(const bf16x8*)(Vb + vOff[kp][dt]);

            f32x4 st[2][2];
#pragma unroll
            for (int sub = 0; sub < 2; sub++) {
                const int kt = kp * 2 + sub;
                const bf16x8 kf0 = *(const bf16x8*)(Kb + kOff[kt][0]);
                const bf16x8 kf1 = *(const bf16x8*)(Kb + kOff[kt][1]);
#pragma unroll
                for (int t = 0; t < 2; t++) {
                    f32x4 a = f32x4{0.f, 0.f, 0.f, 0.f};
                    a = __builtin_amdgcn_mfma_f32_16x16x32_bf16(kf0, qf[t][0], a, 0, 0, 0);
                    a = __builtin_amdgcn_mfma_f32_16x16x32_bf16(kf1, qf[t][1], a, 0, 0, 0);
                    st[t][sub] = a;
                }
            }

#pragma unroll
            for (int t = 0; t < 2; t++) {
                const bf16x8 pbig = exp2_pk(st[t][0], st[t][1]);
                lfrag[t] = __builtin_amdgcn_mfma_f32_16x16x32_bf16(ones8, pbig, lfrag[t], 0, 0, 0);
#pragma unroll
                for (int dt = 0; dt < 4; dt++)
                    oacc[t][dt] = __builtin_amdgcn_mfma_f32_16x16x32_bf16(vf[dt], pbig, oacc[t][dt], 0, 0, 0);
            }
        }
    }

    // direct store: col = query (lane-local l), row band = d
#pragma unroll
    for (int t = 0; t < 2; t++) {
        const float inv = 1.f / lfrag[t][0];
        const size_t qrow = (size_t)(q0 + wave * 32 + t * 16 + l15);
#pragma unroll
        for (int dt = 0; dt < 4; dt++) {
            bf16x4 o4;
#pragma unroll
            for (int r = 0; r < 4; r++) o4[r] = (bf16_t)(oacc[t][dt][r] * inv);
            *(bf16x4*)(O + qrow * D_MODEL + hoff + dt * 16 + lg * 4) = o4;
        }
    }
}

// ---------------- launcher ----------------
extern "C" void kernel_launch(void* const* d_in, const int* in_sizes, int n_in,
                              void* d_out, int out_size, void* d_ws, size_t ws_size,
                              hipStream_t stream) {
    const float* x  = (const float*)d_in[0];
    const float* Wq = (const float*)d_in[1];
    const float* Wk = (const float*)d_in[2];
    const float* Wv = (const float*)d_in[3];
    const float* Wo = (const float*)d_in[4];
    float* out = (float*)d_out;

    char* ws = (char*)d_ws;
    bf16_t* xb  = (bf16_t*)(ws);
    bf16_t* wqb = (bf16_t*)(ws + (8u  << 20));
    bf16_t* wob = (bf16_t*)(ws + (14u << 20));
    bf16_t* Qb  = (bf16_t*)(ws + (16u << 20));
    bf16_t* Kb  = (bf16_t*)(ws + (24u << 20));
    bf16_t* Vtb = (bf16_t*)(ws + (32u << 20));
    bf16_t* Ab  = (bf16_t*)(ws + (40u << 20));

    // fused cast: 1M threads for x (4M elems) + 1M for the 4 weights
    cast_all<<<8192, 256, 0, stream>>>(x, Wq, Wk, Wv, Wo, xb, wqb);

    gemm_lds<1><<<dim3(3 * D_MODEL / 128, SEQ / 128), 256, 0, stream>>>(
        xb, wqb, Qb, Kb, Vtb, SEQ, 3 * D_MODEL, D_MODEL);

    attn_kernel<<<256, 512, 0, stream>>>(Qb, Kb, Vtb, Ab);

    gemm_lds<0><<<dim3(D_MODEL / 128, SEQ / 128), 256, 0, stream>>>(
        Ab, wob, out, nullptr, nullptr, SEQ, D_MODEL, D_MODEL);
}